// Round 6
// baseline (396.462 us; speedup 1.0000x reference)
//
#include <hip/hip_runtime.h>

#define N_NODES 100000
constexpr int F     = 128;
constexpr int NB    = (N_NODES + 63) / 64;  // 1563 buckets of 64 dst-nodes
constexpr int BCAP  = 2496;                 // bucket capacity (mean 2048, +9.9 sigma)
constexpr int LCAP  = 80;                   // per-node LDS CSR cap (max in-deg ~65)
constexpr int CHUNK = 8192;                 // edges per partition block (391 blocks)
constexpr int EPT   = CHUNK / 512;          // 16 edges per thread (registers)
constexpr int PADN  = N_NODES;              // zero-row index for edge-list padding

typedef __attribute__((ext_vector_type(8))) short short8;   // 8 bf16 (4 VGPRs)
typedef __attribute__((ext_vector_type(4))) float f32x4;    // MFMA C/D
typedef __attribute__((ext_vector_type(4))) short short4v;
typedef __attribute__((ext_vector_type(4))) unsigned uint4v;

__device__ inline short f2bf(float v) {
    union { float f; unsigned u; } x; x.f = v;
    unsigned r = (x.u + 0x7fff + ((x.u >> 16) & 1)) >> 16;  // round-nearest-even
    return (short)r;
}

// accumulate both bf16 halves of w into separate f32 accs: 2 VALU instead of 4
// (v_dot2_f32_bf16: D = S0.lo*S1.lo + S0.hi*S1.hi + S2; masks select one half)
__device__ inline void dot2acc(float& alo, float& ahi, unsigned w, unsigned mlo, unsigned mhi) {
    asm("v_dot2_f32_bf16 %0, %1, %2, %0" : "+v"(alo) : "v"(w), "v"(mlo));
    asm("v_dot2_f32_bf16 %0, %1, %2, %0" : "+v"(ahi) : "v"(w), "v"(mhi));
}

// ---------- weight prep (transpose->bf16) ----------
__global__ __launch_bounds__(256) void prep_kernel(const float* __restrict__ W_enc,
                                                   const float* __restrict__ W_gcn,
                                                   const float* __restrict__ W1,
                                                   const float* __restrict__ W2,
                                                   short* __restrict__ Wte,
                                                   short* __restrict__ Wtg,
                                                   short* __restrict__ Wt1,
                                                   short* __restrict__ W2t) {
    int idx = blockIdx.x * 256 + threadIdx.x;
    if (idx < 16384) { int h = idx >> 7, k = idx & 127; Wte[idx] = f2bf(W_enc[k * 128 + h]); return; }
    idx -= 16384;
    if (idx < 16384) { int h = idx >> 7, k = idx & 127; Wtg[idx] = f2bf(W_gcn[k * 128 + h]); return; }
    idx -= 16384;
    if (idx < 32768) { int h = idx >> 7, k = idx & 127; Wt1[idx] = f2bf(W1[k * 256 + h]); return; }
    idx -= 32768;
    if (idx < 4096)  { int n = idx >> 8, k = idx & 255; W2t[idx] = (n < 10) ? f2bf(W2[k * 10 + n]) : (short)0; }
}

// ---------- single-pass partition: edges read once; NO global atomics (r2 lesson) ----
__global__ __launch_bounds__(512, 4) void part_kernel(const int* __restrict__ src,
                                                      const int* __restrict__ dst,
                                                      int* __restrict__ bcur,
                                                      int* __restrict__ part, int E) {
    __shared__ int cnt[NB];
    __shared__ int base[NB];
    for (int b = threadIdx.x; b < NB; b += 512) cnt[b] = 0;
    __syncthreads();
    const int e0 = blockIdx.x * CHUNK;
    const int e1 = min(e0 + CHUNK, E);

    int pk[EPT];    // src | local_dst<<17
    int meta[EPT];  // bucket | pos<<11  (or -1 invalid)
#pragma unroll
    for (int i = 0; i < EPT; ++i) {
        int e = e0 + i * 512 + (int)threadIdx.x;
        meta[i] = -1;
        if (e < e1) {
            int d = dst[e];
            int b = d >> 6;
            pk[i] = src[e] | ((d & 63) << 17);
            int pos = atomicAdd(&cnt[b], 1);
            meta[i] = b | (pos << 11);
        }
    }
    __syncthreads();
    for (int b = threadIdx.x; b < NB; b += 512) {
        int c = cnt[b];
        base[b] = c ? atomicAdd(&bcur[b], c) : 0;
    }
    __syncthreads();
#pragma unroll
    for (int i = 0; i < EPT; ++i) {
        if (meta[i] >= 0) {
            int b = meta[i] & 0x7FF;
            int idx = base[b] + (meta[i] >> 11);
            if (idx < BCAP) part[b * BCAP + idx] = pk[i];
        }
    }
}

// ---------- deg: per-bucket LDS histogram of partition -> dinv = rsqrt(1+deg) ----
__global__ __launch_bounds__(256) void deg_kernel(const int* __restrict__ bcur,
                                                  const int* __restrict__ part,
                                                  float* __restrict__ dinv) {
    __shared__ int deg_l[64];
    const int b = blockIdx.x;
    if (threadIdx.x < 64) deg_l[threadIdx.x] = 0;
    __syncthreads();
    const int cnt = min(bcur[b], BCAP);
    const int* p = part + (size_t)b * BCAP;
#pragma unroll 4
    for (int i = threadIdx.x; i < cnt; i += 256)
        atomicAdd(&deg_l[(p[i] >> 17) & 63], 1);
    __syncthreads();
    if (threadIdx.x < 64)
        dinv[b * 64 + threadIdx.x] = rsqrtf(1.f + (float)deg_l[threadIdx.x]);
}

// ---------- gemmA: [relu(x@We+be)] -> LDS -> [(..@Wg)*dinv] -> xs (no barriers) ----
__global__ __launch_bounds__(256) void gemmA_kernel(const float* __restrict__ x,
                                                    const short* __restrict__ Wte,
                                                    const short* __restrict__ Wtg,
                                                    const float* __restrict__ b_enc,
                                                    const float* __restrict__ dinv,
                                                    short* __restrict__ xs) {
    __shared__ short h_l[4][16][136];  // per-wave private 16x128 tiles (+pad)
    const int b = blockIdx.x;
    const int wave = threadIdx.x >> 6;
    const int lane = threadIdx.x & 63;
    const int quad = lane >> 4;
    const int l16  = lane & 15;
    const int node0 = b * 64 + wave * 16;
    int nrow = node0 + l16;
    const bool valid = nrow < N_NODES;
    if (!valid) nrow = N_NODES - 1;

    const float dvn = dinv[nrow];

    // phase 1: h = relu(x @ W_enc + b_enc) -> LDS (bf16)
    f32x4 acc[8] = {};
#pragma unroll
    for (int kc = 0; kc < 4; ++kc) {
        const float* ap = x + (size_t)nrow * 128 + kc * 32 + quad * 8;
        float4 f0 = *reinterpret_cast<const float4*>(ap);
        float4 f1 = *reinterpret_cast<const float4*>(ap + 4);
        short8 xfrag;
        xfrag.s0 = f2bf(f0.x); xfrag.s1 = f2bf(f0.y); xfrag.s2 = f2bf(f0.z); xfrag.s3 = f2bf(f0.w);
        xfrag.s4 = f2bf(f1.x); xfrag.s5 = f2bf(f1.y); xfrag.s6 = f2bf(f1.z); xfrag.s7 = f2bf(f1.w);
#pragma unroll
        for (int t = 0; t < 8; ++t) {
            short8 wfrag = *reinterpret_cast<const short8*>(Wte + (size_t)(t * 16 + l16) * 128 + kc * 32 + quad * 8);
            acc[t] = __builtin_amdgcn_mfma_f32_16x16x32_bf16(wfrag, xfrag, acc[t], 0, 0, 0);
        }
    }
#pragma unroll
    for (int t = 0; t < 8; ++t) {
        short4v o;
#pragma unroll
        for (int r = 0; r < 4; ++r)
            ((short*)&o)[r] = f2bf(fmaxf(acc[t][r] + b_enc[t * 16 + quad * 4 + r], 0.f));
        *reinterpret_cast<short4v*>(&h_l[wave][l16][t * 16 + quad * 4]) = o;
    }
    // h_l is wave-private; DS ops are in-order per wave -> no barrier needed

    // phase 2: xs = (h @ W_gcn) * dinv[node]  (zero for pad rows)
    f32x4 acc2[8] = {};
#pragma unroll
    for (int kc = 0; kc < 4; ++kc) {
        short8 xfrag = *reinterpret_cast<const short8*>(&h_l[wave][l16][kc * 32 + quad * 8]);
#pragma unroll
        for (int t = 0; t < 8; ++t) {
            short8 wfrag = *reinterpret_cast<const short8*>(Wtg + (size_t)(t * 16 + l16) * 128 + kc * 32 + quad * 8);
            acc2[t] = __builtin_amdgcn_mfma_f32_16x16x32_bf16(wfrag, xfrag, acc2[t], 0, 0, 0);
        }
    }
    const int srow = node0 + l16;
#pragma unroll
    for (int t = 0; t < 8; ++t) {
        short4v o;
#pragma unroll
        for (int r = 0; r < 4; ++r)
            ((short*)&o)[r] = valid ? f2bf(acc2[t][r] * dvn) : (short)0;
        *reinterpret_cast<short4v*>(xs + (size_t)srow * 128 + t * 16 + quad * 4) = o;
    }
}

// ---------- agg: h2 = relu(dv*(sum xs[src] + xs[node]) + b_gcn) ----
// r5 profile: 115us/dispatch, VALUBusy 40%, FETCH 355MB, no pipe saturated ->
// latency + VALU mix. Fix: (1) v_dot2_f32_bf16 halves the unpack+add chain,
// (2) 2-node interleave doubles loads in flight & overlaps shuffle tails.
__global__ __launch_bounds__(512, 4) void agg_kernel(const short* __restrict__ xs,
                                                     const int* __restrict__ bcur,
                                                     const int* __restrict__ part,
                                                     const float* __restrict__ bg,
                                                     short* __restrict__ h2) {
    __shared__ int csr_l[64 * LCAP];   // 20480 B
    __shared__ int cur[64];
    const int b = blockIdx.x;
    const int tid = threadIdx.x;
    if (tid < 64) cur[tid] = 0;
    __syncthreads();
    const int cnt = min(bcur[b], BCAP);
    const int* p = part + (size_t)b * BCAP;
#pragma unroll 4
    for (int i = tid; i < cnt; i += 512) {
        int v = p[i];
        int ld = (v >> 17) & 63;
        int pos = atomicAdd(&cur[ld], 1);
        if (pos < LCAP) csr_l[ld * LCAP + pos] = v & 0x1FFFF;
    }
    __syncthreads();
    if (tid < 64) {  // pad each list to x16 with PADN (zero row)
        int d = min(cur[tid], LCAP);
        int dp = (d + 15) & ~15;
        for (int k = d; k < dp; ++k) csr_l[tid * LCAP + k] = PADN;
    }
    __syncthreads();

    const int wave = tid >> 6;    // 0..7
    const int lane = tid & 63;
    const int g    = lane >> 4;   // edge group
    const int l16  = lane & 15;   // 16 B feature slot
    const uint4v* xs4 = reinterpret_cast<const uint4v*>(xs);
    const float4 bgA = reinterpret_cast<const float4*>(bg)[l16 * 2];
    const float4 bgB = reinterpret_cast<const float4*>(bg)[l16 * 2 + 1];
    unsigned mlo = 0x00003F80u;   // packed bf16 (lo=1.0, hi=0.0)
    unsigned mhi = 0x3F800000u;   // packed bf16 (lo=0.0, hi=1.0)

    for (int t = 0; t < 8; t += 2) {
        const int ld0 = wave * 8 + t;
        const int ld1 = ld0 + 1;
        const int n0  = b * 64 + ld0;
        const int n1  = b * 64 + ld1;
        const int d0 = cur[ld0], d1 = cur[ld1];
        const int dp0 = (min(d0, LCAP) + 15) & ~15;   // 0 for nodes >= N_NODES (cur==0)
        const int dp1 = (min(d1, LCAP) + 15) & ~15;
        const float dv0 = rsqrtf(1.f + (float)d0);
        const float dv1 = rsqrtf(1.f + (float)d1);
        const int* cl0 = csr_l + ld0 * LCAP;
        const int* cl1 = csr_l + ld1 * LCAP;
        const int jm = max(dp0, dp1);

        float a0[8] = {}, a1[8] = {};
        for (int j = 0; j < jm; j += 16) {            // wave-uniform branches below
            uint4v v0[4], v1[4];
            const bool has0 = j < dp0, has1 = j < dp1;
            if (has0) {
                int s[4];
#pragma unroll
                for (int u = 0; u < 4; ++u) s[u] = cl0[j + u * 4 + g];   // 4-addr LDS broadcast
#pragma unroll
                for (int u = 0; u < 4; ++u) v0[u] = xs4[((size_t)s[u] << 4) + l16];
            }
            if (has1) {
                int s[4];
#pragma unroll
                for (int u = 0; u < 4; ++u) s[u] = cl1[j + u * 4 + g];
#pragma unroll
                for (int u = 0; u < 4; ++u) v1[u] = xs4[((size_t)s[u] << 4) + l16];
            }
            if (has0) {
#pragma unroll
                for (int u = 0; u < 4; ++u) {
                    dot2acc(a0[0], a0[1], v0[u].x, mlo, mhi);
                    dot2acc(a0[2], a0[3], v0[u].y, mlo, mhi);
                    dot2acc(a0[4], a0[5], v0[u].z, mlo, mhi);
                    dot2acc(a0[6], a0[7], v0[u].w, mlo, mhi);
                }
            }
            if (has1) {
#pragma unroll
                for (int u = 0; u < 4; ++u) {
                    dot2acc(a1[0], a1[1], v1[u].x, mlo, mhi);
                    dot2acc(a1[2], a1[3], v1[u].y, mlo, mhi);
                    dot2acc(a1[4], a1[5], v1[u].z, mlo, mhi);
                    dot2acc(a1[6], a1[7], v1[u].w, mlo, mhi);
                }
            }
        }

        // combine the 4 edge groups (both nodes), then self-loop + store on g==0
#pragma unroll
        for (int r = 0; r < 8; ++r) {
            a0[r] += __shfl_xor(a0[r], 16, 64); a0[r] += __shfl_xor(a0[r], 32, 64);
            a1[r] += __shfl_xor(a1[r], 16, 64); a1[r] += __shfl_xor(a1[r], 32, 64);
        }
        if (g == 0 && n0 < N_NODES) {
            uint4v vs = xs4[((size_t)n0 << 4) + l16];  // self-loop (pad rows are zero)
            dot2acc(a0[0], a0[1], vs.x, mlo, mhi);
            dot2acc(a0[2], a0[3], vs.y, mlo, mhi);
            dot2acc(a0[4], a0[5], vs.z, mlo, mhi);
            dot2acc(a0[6], a0[7], vs.w, mlo, mhi);
            short8 o;
            o.s0 = f2bf(fmaxf(fmaf(a0[0], dv0, bgA.x), 0.f));
            o.s1 = f2bf(fmaxf(fmaf(a0[1], dv0, bgA.y), 0.f));
            o.s2 = f2bf(fmaxf(fmaf(a0[2], dv0, bgA.z), 0.f));
            o.s3 = f2bf(fmaxf(fmaf(a0[3], dv0, bgA.w), 0.f));
            o.s4 = f2bf(fmaxf(fmaf(a0[4], dv0, bgB.x), 0.f));
            o.s5 = f2bf(fmaxf(fmaf(a0[5], dv0, bgB.y), 0.f));
            o.s6 = f2bf(fmaxf(fmaf(a0[6], dv0, bgB.z), 0.f));
            o.s7 = f2bf(fmaxf(fmaf(a0[7], dv0, bgB.w), 0.f));
            *reinterpret_cast<short8*>(h2 + ((size_t)n0 << 7) + l16 * 8) = o;
        }
        if (g == 0 && n1 < N_NODES) {
            uint4v vs = xs4[((size_t)n1 << 4) + l16];
            dot2acc(a1[0], a1[1], vs.x, mlo, mhi);
            dot2acc(a1[2], a1[3], vs.y, mlo, mhi);
            dot2acc(a1[4], a1[5], vs.z, mlo, mhi);
            dot2acc(a1[6], a1[7], vs.w, mlo, mhi);
            short8 o;
            o.s0 = f2bf(fmaxf(fmaf(a1[0], dv1, bgA.x), 0.f));
            o.s1 = f2bf(fmaxf(fmaf(a1[1], dv1, bgA.y), 0.f));
            o.s2 = f2bf(fmaxf(fmaf(a1[2], dv1, bgA.z), 0.f));
            o.s3 = f2bf(fmaxf(fmaf(a1[3], dv1, bgA.w), 0.f));
            o.s4 = f2bf(fmaxf(fmaf(a1[4], dv1, bgB.x), 0.f));
            o.s5 = f2bf(fmaxf(fmaf(a1[5], dv1, bgB.y), 0.f));
            o.s6 = f2bf(fmaxf(fmaf(a1[6], dv1, bgB.z), 0.f));
            o.s7 = f2bf(fmaxf(fmaf(a1[7], dv1, bgB.w), 0.f));
            *reinterpret_cast<short8*>(h2 + ((size_t)n1 << 7) + l16 * 8) = o;
        }
    }
}

// ---------- gemmB: 2 node-tiles per wave (128 rows/block), weights loaded once ----
__global__ __launch_bounds__(256) void gemmB_kernel(const short* __restrict__ h2,
                                                    const short* __restrict__ Wt1,
                                                    const short* __restrict__ W2t,
                                                    const float* __restrict__ b1,
                                                    const float* __restrict__ b2,
                                                    float* __restrict__ q) {
    __shared__ short hq_l[4][16][264];  // per-wave private 16x256 tile (reused per node-tile)
    const int wave = threadIdx.x >> 6;
    const int lane = threadIdx.x & 63;
    const int quad = lane >> 4;
    const int l16  = lane & 15;
    const int node0 = blockIdx.x * 128 + wave * 32;

    int r0 = node0 + l16;
    int r1 = node0 + 16 + l16;
    if (r0 >= N_NODES) r0 = N_NODES - 1;
    if (r1 >= N_NODES) r1 = N_NODES - 1;

    f32x4 acc0[16] = {}, acc1[16] = {};
#pragma unroll
    for (int kc = 0; kc < 4; ++kc) {
        short8 xf0 = *reinterpret_cast<const short8*>(h2 + (size_t)r0 * 128 + kc * 32 + quad * 8);
        short8 xf1 = *reinterpret_cast<const short8*>(h2 + (size_t)r1 * 128 + kc * 32 + quad * 8);
#pragma unroll
        for (int t = 0; t < 16; ++t) {
            short8 wfrag = *reinterpret_cast<const short8*>(Wt1 + (size_t)(t * 16 + l16) * 128 + kc * 32 + quad * 8);
            acc0[t] = __builtin_amdgcn_mfma_f32_16x16x32_bf16(wfrag, xf0, acc0[t], 0, 0, 0);
            acc1[t] = __builtin_amdgcn_mfma_f32_16x16x32_bf16(wfrag, xf1, acc1[t], 0, 0, 0);
        }
    }

#pragma unroll
    for (int half = 0; half < 2; ++half) {
        const f32x4* acc = half ? acc1 : acc0;
        const int nb = node0 + half * 16;
#pragma unroll
        for (int t = 0; t < 16; ++t) {
            short4v o;
#pragma unroll
            for (int r = 0; r < 4; ++r)
                ((short*)&o)[r] = f2bf(fmaxf(acc[t][r] + b1[t * 16 + quad * 4 + r], 0.f));
            *reinterpret_cast<short4v*>(&hq_l[wave][l16][t * 16 + quad * 4]) = o;
        }
        // wave-private tile; DS ops are in-order per wave -> no barrier needed

        f32x4 a2 = {};
#pragma unroll
        for (int kc = 0; kc < 8; ++kc) {
            short8 afrag = *reinterpret_cast<const short8*>(&hq_l[wave][l16][kc * 32 + quad * 8]);
            short8 bfrag = *reinterpret_cast<const short8*>(W2t + (size_t)l16 * 256 + kc * 32 + quad * 8);
            a2 = __builtin_amdgcn_mfma_f32_16x16x32_bf16(afrag, bfrag, a2, 0, 0, 0);
        }
        if (l16 < 10) {
            float bv = b2[l16];
#pragma unroll
            for (int r = 0; r < 4; ++r) {
                int nd = nb + quad * 4 + r;
                if (nd < N_NODES) q[(size_t)nd * 10 + l16] = a2[r] + bv;
            }
        }
    }
}

extern "C" void kernel_launch(void* const* d_in, const int* in_sizes, int n_in,
                              void* d_out, int out_size, void* d_ws, size_t ws_size,
                              hipStream_t stream) {
    const float* x     = (const float*)d_in[0];
    const int*   ei    = (const int*)d_in[1];
    const float* W_enc = (const float*)d_in[2];
    const float* b_enc = (const float*)d_in[3];
    const float* W_gcn = (const float*)d_in[4];
    const float* b_gcn = (const float*)d_in[5];
    const float* W1    = (const float*)d_in[6];
    const float* b1    = (const float*)d_in[7];
    const float* W2    = (const float*)d_in[8];
    const float* b2    = (const float*)d_in[9];
    float* q = (float*)d_out;

    const int E = in_sizes[1] / 2;
    const int* srcv = ei;
    const int* dstv = ei + E;

    // workspace layout (bytes)
    char* ws = (char*)d_ws;
    const size_t XSB = (size_t)(NB * 64) * 128 * sizeof(short);  // 25,608,192 (incl. pad rows)
    short* xs  = (short*)(ws);
    short* h2  = (short*)(ws + XSB);
    int*   part= (int*)  (ws + 2 * XSB);                         // NB*BCAP*4 = 15,604,992
    char*  tail = ws + 2 * XSB + (size_t)NB * BCAP * sizeof(int);
    int*   bcr = (int*)(tail);                                   // 8 KB slot
    float* dinv= (float*)(tail + 8192);                          // 400,384 B slot (NB*64 floats)
    short* Wte = (short*)(tail + 408576);
    short* Wtg = (short*)(tail + 441344);
    short* Wt1 = (short*)(tail + 474112);
    short* W2t = (short*)(tail + 539648);
    // end ~= 67.4 MB

    hipMemsetAsync(bcr, 0, 8192, stream);  // bucket cursors only
    prep_kernel<<<272, 256, 0, stream>>>(W_enc, W_gcn, W1, W2, Wte, Wtg, Wt1, W2t);
    part_kernel<<<(E + CHUNK - 1) / CHUNK, 512, 0, stream>>>(srcv, dstv, bcr, part, E);
    deg_kernel<<<NB, 256, 0, stream>>>(bcr, part, dinv);
    gemmA_kernel<<<NB, 256, 0, stream>>>(x, Wte, Wtg, b_enc, dinv, xs);
    agg_kernel<<<NB, 512, 0, stream>>>(xs, bcr, part, b_gcn, h2);
    gemmB_kernel<<<(N_NODES + 127) / 128, 256, 0, stream>>>(h2, Wt1, W2t, b1, b2, q);
}

// Round 8
// 377.326 us; speedup vs baseline: 1.0507x; 1.0507x over previous
//
#include <hip/hip_runtime.h>

#define N_NODES 100000
constexpr int F     = 128;
constexpr int NB    = (N_NODES + 63) / 64;  // 1563 buckets of 64 dst-nodes
constexpr int BCAP  = 2496;                 // bucket capacity (mean 2048, +9.9 sigma)
constexpr int LCAP  = 80;                   // per-node LDS CSR cap (max in-deg ~65)
constexpr int CHUNK = 8192;                 // edges per partition block (391 blocks)
constexpr int EPT   = CHUNK / 512;          // 16 edges per thread (registers)
constexpr int PADN  = N_NODES;              // zero-row index for edge-list padding

typedef __attribute__((ext_vector_type(8))) short short8;   // 8 bf16 (4 VGPRs)
typedef __attribute__((ext_vector_type(4))) float f32x4;    // MFMA C/D
typedef __attribute__((ext_vector_type(4))) short short4v;
typedef __attribute__((ext_vector_type(4))) unsigned uint4v;

__device__ inline short f2bf(float v) {
    union { float f; unsigned u; } x; x.f = v;
    unsigned r = (x.u + 0x7fff + ((x.u >> 16) & 1)) >> 16;  // round-nearest-even
    return (short)r;
}

// accumulate both bf16 halves of w into separate f32 accs: 2 VALU instead of 4
// (v_dot2_f32_bf16: D = S0.lo*S1.lo + S0.hi*S1.hi + S2; masks select one half)
__device__ inline void dot2acc(float& alo, float& ahi, unsigned w, unsigned mlo, unsigned mhi) {
    asm("v_dot2_f32_bf16 %0, %1, %2, %0" : "+v"(alo) : "v"(w), "v"(mlo));
    asm("v_dot2_f32_bf16 %0, %1, %2, %0" : "+v"(ahi) : "v"(w), "v"(mhi));
}

// ---------- weight prep (transpose->bf16) + bcr zeroing ----------
__global__ __launch_bounds__(256) void prep_kernel(const float* __restrict__ W_enc,
                                                   const float* __restrict__ W_gcn,
                                                   const float* __restrict__ W1,
                                                   const float* __restrict__ W2,
                                                   short* __restrict__ Wte,
                                                   short* __restrict__ Wtg,
                                                   short* __restrict__ Wt1,
                                                   short* __restrict__ W2t,
                                                   int* __restrict__ bcr) {
    int idx = blockIdx.x * 256 + threadIdx.x;
    if (idx < 16384) { int h = idx >> 7, k = idx & 127; Wte[idx] = f2bf(W_enc[k * 128 + h]); return; }
    idx -= 16384;
    if (idx < 16384) { int h = idx >> 7, k = idx & 127; Wtg[idx] = f2bf(W_gcn[k * 128 + h]); return; }
    idx -= 16384;
    if (idx < 32768) { int h = idx >> 7, k = idx & 127; Wt1[idx] = f2bf(W1[k * 256 + h]); return; }
    idx -= 32768;
    if (idx < 4096)  { int n = idx >> 8, k = idx & 255; W2t[idx] = (n < 10) ? f2bf(W2[k * 10 + n]) : (short)0; return; }
    idx -= 4096;
    if (idx < NB) bcr[idx] = 0;
}

// ---------- single-pass partition: edges read once; NO global atomics (r2 lesson) ----
__global__ __launch_bounds__(512, 4) void part_kernel(const int* __restrict__ src,
                                                      const int* __restrict__ dst,
                                                      int* __restrict__ bcur,
                                                      int* __restrict__ part, int E) {
    __shared__ int cnt[NB];
    __shared__ int base[NB];
    for (int b = threadIdx.x; b < NB; b += 512) cnt[b] = 0;
    __syncthreads();
    const int e0 = blockIdx.x * CHUNK;
    const int e1 = min(e0 + CHUNK, E);

    int pk[EPT];    // src | local_dst<<17
    int meta[EPT];  // bucket | pos<<11  (or -1 invalid)
#pragma unroll
    for (int i = 0; i < EPT; ++i) {
        int e = e0 + i * 512 + (int)threadIdx.x;
        meta[i] = -1;
        if (e < e1) {
            int d = dst[e];
            int b = d >> 6;
            pk[i] = src[e] | ((d & 63) << 17);
            int pos = atomicAdd(&cnt[b], 1);
            meta[i] = b | (pos << 11);
        }
    }
    __syncthreads();
    for (int b = threadIdx.x; b < NB; b += 512) {
        int c = cnt[b];
        base[b] = c ? atomicAdd(&bcur[b], c) : 0;
    }
    __syncthreads();
#pragma unroll
    for (int i = 0; i < EPT; ++i) {
        if (meta[i] >= 0) {
            int b = meta[i] & 0x7FF;
            int idx = base[b] + (meta[i] >> 11);
            if (idx < BCAP) part[b * BCAP + idx] = pk[i];
        }
    }
}

// ---------- deg: per-bucket LDS histogram of partition -> dinv = rsqrt(1+deg) ----
__global__ __launch_bounds__(256) void deg_kernel(const int* __restrict__ bcur,
                                                  const int* __restrict__ part,
                                                  float* __restrict__ dinv) {
    __shared__ int deg_l[64];
    const int b = blockIdx.x;
    if (threadIdx.x < 64) deg_l[threadIdx.x] = 0;
    __syncthreads();
    const int cnt = min(bcur[b], BCAP);
    const int* p = part + (size_t)b * BCAP;
#pragma unroll 4
    for (int i = threadIdx.x; i < cnt; i += 256)
        atomicAdd(&deg_l[(p[i] >> 17) & 63], 1);
    __syncthreads();
    if (threadIdx.x < 64)
        dinv[b * 64 + threadIdx.x] = rsqrtf(1.f + (float)deg_l[threadIdx.x]);
}

// ---------- gemmA: [relu(x@We+be)] -> LDS -> [(..@Wg)*dinv] -> xs (no barriers) ----
__global__ __launch_bounds__(256) void gemmA_kernel(const float* __restrict__ x,
                                                    const short* __restrict__ Wte,
                                                    const short* __restrict__ Wtg,
                                                    const float* __restrict__ b_enc,
                                                    const float* __restrict__ dinv,
                                                    short* __restrict__ xs) {
    __shared__ short h_l[4][16][136];  // per-wave private 16x128 tiles (+pad)
    const int b = blockIdx.x;
    const int wave = threadIdx.x >> 6;
    const int lane = threadIdx.x & 63;
    const int quad = lane >> 4;
    const int l16  = lane & 15;
    const int node0 = b * 64 + wave * 16;
    int nrow = node0 + l16;
    const bool valid = nrow < N_NODES;
    if (!valid) nrow = N_NODES - 1;

    const float dvn = dinv[nrow];

    // phase 1: h = relu(x @ W_enc + b_enc) -> LDS (bf16)
    f32x4 acc[8] = {};
#pragma unroll
    for (int kc = 0; kc < 4; ++kc) {
        const float* ap = x + (size_t)nrow * 128 + kc * 32 + quad * 8;
        float4 f0 = *reinterpret_cast<const float4*>(ap);
        float4 f1 = *reinterpret_cast<const float4*>(ap + 4);
        short8 xfrag;
        xfrag.s0 = f2bf(f0.x); xfrag.s1 = f2bf(f0.y); xfrag.s2 = f2bf(f0.z); xfrag.s3 = f2bf(f0.w);
        xfrag.s4 = f2bf(f1.x); xfrag.s5 = f2bf(f1.y); xfrag.s6 = f2bf(f1.z); xfrag.s7 = f2bf(f1.w);
#pragma unroll
        for (int t = 0; t < 8; ++t) {
            short8 wfrag = *reinterpret_cast<const short8*>(Wte + (size_t)(t * 16 + l16) * 128 + kc * 32 + quad * 8);
            acc[t] = __builtin_amdgcn_mfma_f32_16x16x32_bf16(wfrag, xfrag, acc[t], 0, 0, 0);
        }
    }
#pragma unroll
    for (int t = 0; t < 8; ++t) {
        short4v o;
#pragma unroll
        for (int r = 0; r < 4; ++r)
            ((short*)&o)[r] = f2bf(fmaxf(acc[t][r] + b_enc[t * 16 + quad * 4 + r], 0.f));
        *reinterpret_cast<short4v*>(&h_l[wave][l16][t * 16 + quad * 4]) = o;
    }
    // h_l is wave-private; DS ops are in-order per wave -> no barrier needed

    // phase 2: xs = (h @ W_gcn) * dinv[node]  (zero for pad rows)
    f32x4 acc2[8] = {};
#pragma unroll
    for (int kc = 0; kc < 4; ++kc) {
        short8 xfrag = *reinterpret_cast<const short8*>(&h_l[wave][l16][kc * 32 + quad * 8]);
#pragma unroll
        for (int t = 0; t < 8; ++t) {
            short8 wfrag = *reinterpret_cast<const short8*>(Wtg + (size_t)(t * 16 + l16) * 128 + kc * 32 + quad * 8);
            acc2[t] = __builtin_amdgcn_mfma_f32_16x16x32_bf16(wfrag, xfrag, acc2[t], 0, 0, 0);
        }
    }
    const int srow = node0 + l16;
#pragma unroll
    for (int t = 0; t < 8; ++t) {
        short4v o;
#pragma unroll
        for (int r = 0; r < 4; ++r)
            ((short*)&o)[r] = valid ? f2bf(acc2[t][r] * dvn) : (short)0;
        *reinterpret_cast<short4v*>(xs + (size_t)srow * 128 + t * 16 + quad * 4) = o;
    }
}

// ---------- agg: h2 = relu(dv*(sum xs[src] + xs[node]) + b_gcn) ----
// r5/r6 post-mortem: VALU cut (40->31%) flat; depth x occupancy const -> flat.
// => latency-bound, grid-limited (1563 blocks = 6.1/CU, occ 62%). Fix: split
// the feature dim across sibling blocks (grid 2xNB); each handles 128B of
// every edge row (16 lanes x uint2, still line-coalesced). Same total lines.
__global__ __launch_bounds__(512, 8) void agg_kernel(const short* __restrict__ xs,
                                                     const int* __restrict__ bcur,
                                                     const int* __restrict__ part,
                                                     const float* __restrict__ bg,
                                                     short* __restrict__ h2) {
    __shared__ int csr_l[64 * LCAP];   // 20480 B
    __shared__ int cur[64];
    const int b    = blockIdx.x >> 1;
    const int half = blockIdx.x & 1;
    const int tid = threadIdx.x;
    if (tid < 64) cur[tid] = 0;
    __syncthreads();
    const int cnt = min(bcur[b], BCAP);
    const int* p = part + (size_t)b * BCAP;
#pragma unroll 4
    for (int i = tid; i < cnt; i += 512) {
        int v = p[i];
        int ld = (v >> 17) & 63;
        int pos = atomicAdd(&cur[ld], 1);
        if (pos < LCAP) csr_l[ld * LCAP + pos] = v & 0x1FFFF;
    }
    __syncthreads();
    if (tid < 64) {  // pad each list to x16 with PADN (zero row)
        int d = min(cur[tid], LCAP);
        int dp = (d + 15) & ~15;
        for (int k = d; k < dp; ++k) csr_l[tid * LCAP + k] = PADN;
    }
    __syncthreads();

    const int wave = tid >> 6;    // 0..7
    const int lane = tid & 63;
    const int g    = lane >> 4;   // edge group
    const int l16  = lane & 15;   // 8 B feature slot within the 128 B half-row
    const uint2* xs2 = reinterpret_cast<const uint2*>(xs);
    const int fo = half * 16 + l16;   // uint2 index within the 256 B row (32/row)
    const float4 bgv = reinterpret_cast<const float4*>(bg)[fo];
    unsigned mlo = 0x00003F80u;   // packed bf16 (lo=1.0, hi=0.0)
    unsigned mhi = 0x3F800000u;   // packed bf16 (lo=0.0, hi=1.0)

    for (int t = 0; t < 8; ++t) {
        const int ld = wave * 8 + t;
        const int node = b * 64 + ld;
        if (node >= N_NODES) break;  // wave-uniform

        const int dtrue = cur[ld];
        const int dpad = (min(dtrue, LCAP) + 15) & ~15;
        const float dv = rsqrtf(1.f + (float)dtrue);
        const int* cl = csr_l + ld * LCAP;

        float a0 = 0.f, a1 = 0.f, a2 = 0.f, a3 = 0.f;
        for (int j = 0; j < dpad; j += 16) {
            int s[4];
            uint2 v[4];
#pragma unroll
            for (int u = 0; u < 4; ++u) s[u] = cl[j + u * 4 + g];   // 4-addr LDS broadcast
#pragma unroll
            for (int u = 0; u < 4; ++u) v[u] = xs2[(size_t)s[u] * 32 + fo];  // 4 in flight
#pragma unroll
            for (int u = 0; u < 4; ++u) {
                dot2acc(a0, a1, v[u].x, mlo, mhi);
                dot2acc(a2, a3, v[u].y, mlo, mhi);
            }
        }
        // combine the 4 edge groups
        a0 += __shfl_xor(a0, 16, 64); a0 += __shfl_xor(a0, 32, 64);
        a1 += __shfl_xor(a1, 16, 64); a1 += __shfl_xor(a1, 32, 64);
        a2 += __shfl_xor(a2, 16, 64); a2 += __shfl_xor(a2, 32, 64);
        a3 += __shfl_xor(a3, 16, 64); a3 += __shfl_xor(a3, 32, 64);
        if (g == 0) {
            uint2 vs = xs2[(size_t)node * 32 + fo];   // self-loop (pad rows are zero)
            dot2acc(a0, a1, vs.x, mlo, mhi);
            dot2acc(a2, a3, vs.y, mlo, mhi);
            short4v o;
            ((short*)&o)[0] = f2bf(fmaxf(fmaf(a0, dv, bgv.x), 0.f));
            ((short*)&o)[1] = f2bf(fmaxf(fmaf(a1, dv, bgv.y), 0.f));
            ((short*)&o)[2] = f2bf(fmaxf(fmaf(a2, dv, bgv.z), 0.f));
            ((short*)&o)[3] = f2bf(fmaxf(fmaf(a3, dv, bgv.w), 0.f));
            *reinterpret_cast<short4v*>(h2 + ((size_t)node << 7) + fo * 4) = o;
        }
    }
}

// ---------- gemmB: 2 node-tiles per wave (128 rows/block), weights loaded once ----
__global__ __launch_bounds__(256) void gemmB_kernel(const short* __restrict__ h2,
                                                    const short* __restrict__ Wt1,
                                                    const short* __restrict__ W2t,
                                                    const float* __restrict__ b1,
                                                    const float* __restrict__ b2,
                                                    float* __restrict__ q) {
    __shared__ short hq_l[4][16][264];  // per-wave private 16x256 tile (reused per node-tile)
    const int wave = threadIdx.x >> 6;
    const int lane = threadIdx.x & 63;
    const int quad = lane >> 4;
    const int l16  = lane & 15;
    const int node0 = blockIdx.x * 128 + wave * 32;

    int r0 = node0 + l16;
    int r1 = node0 + 16 + l16;
    if (r0 >= N_NODES) r0 = N_NODES - 1;
    if (r1 >= N_NODES) r1 = N_NODES - 1;

    f32x4 acc0[16] = {}, acc1[16] = {};
#pragma unroll
    for (int kc = 0; kc < 4; ++kc) {
        short8 xf0 = *reinterpret_cast<const short8*>(h2 + (size_t)r0 * 128 + kc * 32 + quad * 8);
        short8 xf1 = *reinterpret_cast<const short8*>(h2 + (size_t)r1 * 128 + kc * 32 + quad * 8);
#pragma unroll
        for (int t = 0; t < 16; ++t) {
            short8 wfrag = *reinterpret_cast<const short8*>(Wt1 + (size_t)(t * 16 + l16) * 128 + kc * 32 + quad * 8);
            acc0[t] = __builtin_amdgcn_mfma_f32_16x16x32_bf16(wfrag, xf0, acc0[t], 0, 0, 0);
            acc1[t] = __builtin_amdgcn_mfma_f32_16x16x32_bf16(wfrag, xf1, acc1[t], 0, 0, 0);
        }
    }

#pragma unroll
    for (int half = 0; half < 2; ++half) {
        const f32x4* acc = half ? acc1 : acc0;
        const int nb = node0 + half * 16;
#pragma unroll
        for (int t = 0; t < 16; ++t) {
            short4v o;
#pragma unroll
            for (int r = 0; r < 4; ++r)
                ((short*)&o)[r] = f2bf(fmaxf(acc[t][r] + b1[t * 16 + quad * 4 + r], 0.f));
            *reinterpret_cast<short4v*>(&hq_l[wave][l16][t * 16 + quad * 4]) = o;
        }
        // wave-private tile; DS ops are in-order per wave -> no barrier needed

        f32x4 a2 = {};
#pragma unroll
        for (int kc = 0; kc < 8; ++kc) {
            short8 afrag = *reinterpret_cast<const short8*>(&hq_l[wave][l16][kc * 32 + quad * 8]);
            short8 bfrag = *reinterpret_cast<const short8*>(W2t + (size_t)l16 * 256 + kc * 32 + quad * 8);
            a2 = __builtin_amdgcn_mfma_f32_16x16x32_bf16(afrag, bfrag, a2, 0, 0, 0);
        }
        if (l16 < 10) {
            float bv = b2[l16];
#pragma unroll
            for (int r = 0; r < 4; ++r) {
                int nd = nb + quad * 4 + r;
                if (nd < N_NODES) q[(size_t)nd * 10 + l16] = a2[r] + bv;
            }
        }
    }
}

extern "C" void kernel_launch(void* const* d_in, const int* in_sizes, int n_in,
                              void* d_out, int out_size, void* d_ws, size_t ws_size,
                              hipStream_t stream) {
    const float* x     = (const float*)d_in[0];
    const int*   ei    = (const int*)d_in[1];
    const float* W_enc = (const float*)d_in[2];
    const float* b_enc = (const float*)d_in[3];
    const float* W_gcn = (const float*)d_in[4];
    const float* b_gcn = (const float*)d_in[5];
    const float* W1    = (const float*)d_in[6];
    const float* b1    = (const float*)d_in[7];
    const float* W2    = (const float*)d_in[8];
    const float* b2    = (const float*)d_in[9];
    float* q = (float*)d_out;

    const int E = in_sizes[1] / 2;
    const int* srcv = ei;
    const int* dstv = ei + E;

    // workspace layout (bytes)
    char* ws = (char*)d_ws;
    const size_t XSB = (size_t)(NB * 64) * 128 * sizeof(short);  // 25,608,192 (incl. pad rows)
    short* xs  = (short*)(ws);
    short* h2  = (short*)(ws + XSB);
    int*   part= (int*)  (ws + 2 * XSB);                         // NB*BCAP*4 = 15,604,992
    char*  tail = ws + 2 * XSB + (size_t)NB * BCAP * sizeof(int);
    int*   bcr = (int*)(tail);                                   // 8 KB slot
    float* dinv= (float*)(tail + 8192);                          // 400,384 B slot (NB*64 floats)
    short* Wte = (short*)(tail + 408576);
    short* Wtg = (short*)(tail + 441344);
    short* Wt1 = (short*)(tail + 474112);
    short* W2t = (short*)(tail + 539648);
    // end ~= 67.4 MB

    prep_kernel<<<279, 256, 0, stream>>>(W_enc, W_gcn, W1, W2, Wte, Wtg, Wt1, W2t, bcr);
    part_kernel<<<(E + CHUNK - 1) / CHUNK, 512, 0, stream>>>(srcv, dstv, bcr, part, E);
    deg_kernel<<<NB, 256, 0, stream>>>(bcr, part, dinv);
    gemmA_kernel<<<NB, 256, 0, stream>>>(x, Wte, Wtg, b_enc, dinv, xs);
    agg_kernel<<<2 * NB, 512, 0, stream>>>(xs, bcr, part, b_gcn, h2);
    gemmB_kernel<<<(N_NODES + 127) / 128, 256, 0, stream>>>(h2, Wt1, W2t, b1, b2, q);
}